// Round 3
// baseline (393.074 us; speedup 1.0000x reference)
//
#include <hip/hip_runtime.h>
#include <hip/hip_bf16.h>

typedef unsigned short u16;
typedef unsigned int   u32;
typedef short  short8v __attribute__((ext_vector_type(8)));
typedef u16    u16x8   __attribute__((ext_vector_type(8)));
typedef float  f32x16  __attribute__((ext_vector_type(16)));
typedef float  f32x4v  __attribute__((ext_vector_type(4)));
typedef u32    u32x2   __attribute__((ext_vector_type(2)));
typedef u32    u32x4   __attribute__((ext_vector_type(4)));

#define HEADS 64
#define DMODEL 128
#define SEQ 2048

// ---------- helpers ----------

__device__ __forceinline__ f32x16 mfma_bf16(short8v a, short8v b, f32x16 c) {
  return __builtin_amdgcn_mfma_f32_32x32x16_bf16(a, b, c, 0, 0, 0);
}

__device__ __forceinline__ f32x16 fzero16() {
  f32x16 z;
#pragma unroll
  for (int i = 0; i < 16; ++i) z[i] = 0.f;
  return z;
}

__device__ __forceinline__ float fast_exp2(float x) {
  float r;
  asm("v_exp_f32 %0, %1" : "=v"(r) : "v"(x));   // v_exp_f32 IS exp2
  return r;
}

// round-to-nearest-even f32 -> bf16 bits (used in prep/epilogue, not hot loop)
__device__ __forceinline__ u32 bfround(float x) {
  u32 u = __builtin_bit_cast(u32, x);
  u += 0x7fffu + ((u >> 16) & 1u);
  return u >> 16;
}
__device__ __forceinline__ u32 bfpair(float lo, float hi) {
  u32 a = __builtin_bit_cast(u32, lo); a += 0x7fffu + ((a >> 16) & 1u);
  u32 b = __builtin_bit_cast(u32, hi); b += 0x7fffu + ((b >> 16) & 1u);
  return (a >> 16) | (b & 0xffff0000u);
}
// hot-loop pack: scalar casts -> compiler emits v_cvt_pk_bf16_f32 (m240)
__device__ __forceinline__ u32 packbf(float lo, float hi) {
  u32 l16 = (u32)__builtin_bit_cast(u16, __float2bfloat16(lo));
  u32 h16 = (u32)__builtin_bit_cast(u16, __float2bfloat16(hi));
  return l16 | (h16 << 16);
}

// async global->LDS, 16B per lane, dest = uniform base + lane*16
typedef const __attribute__((address_space(1))) void* gp1_t;
typedef __attribute__((address_space(3))) void* lp3_t;
__device__ __forceinline__ void gload16(const u16* g, u16* l) {
  __builtin_amdgcn_global_load_lds((gp1_t)g, (lp3_t)l, 16, 0, 0);
}

// Transposing stage for K prologue only: src [128 d][2048 pos] f32.
// Writes LDS tile [64 pos][128 d] bf16, chunk' = chunk ^ (row&7).
__device__ __forceinline__ void stage_T(const float* __restrict__ src, int pos0,
                                        u16* lds, int tid) {
  int ic = tid & 7;
  int d0 = (tid >> 3) * 2;
  const float* p = src + d0 * SEQ + pos0 + ic * 8;
  f32x4v xa = *reinterpret_cast<const f32x4v*>(p);
  f32x4v xb = *reinterpret_cast<const f32x4v*>(p + 4);
  f32x4v ya = *reinterpret_cast<const f32x4v*>(p + SEQ);
  f32x4v yb = *reinterpret_cast<const f32x4v*>(p + SEQ + 4);
  u32* lds32 = reinterpret_cast<u32*>(lds);
  int cc = d0 >> 3;
#pragma unroll
  for (int k = 0; k < 8; ++k) {
    int r = ic * 8 + k;
    int c2 = cc ^ (r & 7);
    float xv = (k < 4) ? xa[k & 3] : xb[k & 3];
    float yv = (k < 4) ? ya[k & 3] : yb[k & 3];
    lds32[(r * 128 + c2 * 8 + (d0 & 7)) >> 1] = bfpair(xv, yv);
  }
}

// fragment reads (ds_read_b128), undoing the XOR swizzle
__device__ __forceinline__ short8v ld_at(const u16* lds, int row, int chunk) {
  return *reinterpret_cast<const short8v*>(lds + row * 128 + ((chunk ^ (row & 7)) * 8));
}
__device__ __forceinline__ short8v ld_vt(const u16* lds, int d, int chunk) {
  return *reinterpret_cast<const short8v*>(lds + d * 64 + ((chunk ^ (d & 7)) * 8));
}

// ---------- prep kernels ----------

// Q f32 [n][128 d][2048 s] -> Qt bf16 [n][2048 s][128 d]  (natural, no swizzle)
__global__ __launch_bounds__(256) void prep_qt(const float* __restrict__ Q,
                                               u16* __restrict__ Qt) {
  int blk = blockIdx.x;            // 64 heads * 32 pos-tiles
  int n = blk >> 5, pt = blk & 31;
  const float* src = Q + (size_t)n * DMODEL * SEQ;
  u16* dst = Qt + (size_t)n * SEQ * DMODEL + (size_t)pt * 64 * DMODEL;
  int t = threadIdx.x;
  int pq = t & 15, dq = t >> 4;
#pragma unroll
  for (int p = 0; p < 2; ++p) {
    int d0 = (dq + 16 * p) * 4;
    const float* s0 = src + (size_t)d0 * SEQ + pt * 64 + pq * 4;
    f32x4v r0 = *reinterpret_cast<const f32x4v*>(s0);
    f32x4v r1 = *reinterpret_cast<const f32x4v*>(s0 + SEQ);
    f32x4v r2 = *reinterpret_cast<const f32x4v*>(s0 + 2 * SEQ);
    f32x4v r3 = *reinterpret_cast<const f32x4v*>(s0 + 3 * SEQ);
#pragma unroll
    for (int j = 0; j < 4; ++j) {
      u32x2 v = { bfpair(r0[j], r1[j]), bfpair(r2[j], r3[j]) };
      *reinterpret_cast<u32x2*>(dst + (pq * 4 + j) * DMODEL + d0) = v;
    }
  }
}

// V f32 -> bf16, elementwise (layout preserved [n][128 d][2048 s])
__global__ __launch_bounds__(256) void prep_v(const float* __restrict__ V,
                                              u16* __restrict__ V16) {
  size_t e = ((size_t)blockIdx.x * 256 + threadIdx.x) * 8;
  f32x4v a = *reinterpret_cast<const f32x4v*>(V + e);
  f32x4v b = *reinterpret_cast<const f32x4v*>(V + e + 4);
  u32x4 v = { bfpair(a[0], a[1]), bfpair(a[2], a[3]),
              bfpair(b[0], b[1]), bfpair(b[2], b[3]) };
  *reinterpret_cast<u32x4*>(V16 + e) = v;
}

// W transpose (f32 [2048][128] -> bf16 [128][2048])
__global__ void wtrans_kernel(const float* __restrict__ Wsrc, u16* __restrict__ Wt) {
  int e = blockIdx.x * 256 + threadIdx.x;
#pragma unroll
  for (int rr = 0; rr < 2; ++rr) {
    int o = e + rr * 131072;
    int dm = o >> 11, c = o & 2047;
    Wt[o] = (u16)bfround(Wsrc[c * 128 + dm]);
  }
}

// ---------- flash attention (softmax over i, per column j) ----------
// 512 blocks = head(64) x jblock(8 x 256 j), head%8 -> XCD. 8 waves, 32 j/wave.
// LDS: double buffer, each 32KB = AT[64 pos][128 d] + VT[128 d][64 i].
#define BUFW (64 * 128 + 128 * 64)   // u16 per buffer (16KB + 16KB)

__global__ __launch_bounds__(512, 4) void attn_kernel(
    const u16* __restrict__ Qt, const float* __restrict__ K,
    const u16* __restrict__ V16, u16* __restrict__ Ows) {
  __shared__ __align__(16) u16 LDS[2][BUFW];
  const int tid = threadIdx.x;
  const int w = tid >> 6;
  const int lane = tid & 63;
  const int g = lane >> 5;
  const int lj = lane & 31;
  const int p_ = blockIdx.x;
  const int n = ((p_ >> 6) << 3) | (p_ & 7);
  const int j0 = ((p_ >> 3) & 7) * 256;
  const u16* Qtn = Qt + (size_t)n * SEQ * DMODEL;
  const float* Kb = K + (size_t)n * DMODEL * SEQ;
  const u16* Vn = V16 + (size_t)n * DMODEL * SEQ;

  // per-wave staging lane constants (4 gload16 per wave per tile)
  // waves 0-3: Q-tile (16KB): inst idx = w*4+i covers pos = idx*4 + (lane>>4)
  // waves 4-7: V-tile (16KB): inst idx = (w-4)*4+i covers d = idx*8 + (lane>>3)
  int qoff[4], voff[4];
#pragma unroll
  for (int i = 0; i < 4; ++i) {
    int qidx = (w & 3) * 4 + i;
    int pos = qidx * 4 + (lane >> 4);
    int cgq = (lane & 15) ^ (pos & 7);
    qoff[i] = pos * DMODEL + cgq * 8;          // u16 offset within Q tile
    int vidx = (w & 3) * 4 + i;
    int d = vidx * 8 + (lane >> 3);
    int cgv = (lane & 7) ^ (d & 7);
    voff[i] = d * SEQ + cgv * 8;               // u16 offset from V16 row base
  }

  // kick off tile 0 staging into buffer 0 (drained by prologue barriers)
  {
    u16* AT0 = LDS[0];
    u16* VT0 = LDS[0] + 64 * 128;
    if (w < 4) {
#pragma unroll
      for (int i = 0; i < 4; ++i)
        gload16(Qtn + qoff[i], AT0 + ((w & 3) * 4 + i) * 512);
    } else {
#pragma unroll
      for (int i = 0; i < 4; ++i)
        gload16(Vn + voff[i], VT0 + ((w & 3) * 4 + i) * 512);
    }
  }

  // --- K prologue: this wave's 32 K-rows (j) into registers, k(=d)-contiguous ---
  short8v bq[8];
#pragma unroll 1
  for (int p = 0; p < 4; ++p) {
    stage_T(Kb, j0 + p * 64, LDS[1], tid);   // scratch in buf1 AT area
    __syncthreads();
    if ((w >> 1) == p) {
      int row = (w & 1) * 32 + lj;
#pragma unroll
      for (int c = 0; c < 8; ++c) bq[c] = ld_at(LDS[1], row, 2 * c + g);
    }
    __syncthreads();
  }

  f32x16 o0 = fzero16(), o1 = fzero16(), o2 = fzero16(), o3 = fzero16();
  float m_run = -1e30f, l_run = 0.f;
  const float SC = (float)(1.4426950408889634 / 11.313708498984761); // log2e/sqrt(128)

#pragma unroll 1
  for (int ib = 0; ib < 32; ++ib) {
    u16* curAT = LDS[ib & 1];
    u16* curVT = curAT + 64 * 128;
    u16* nxtAT = LDS[(ib & 1) ^ 1];
    u16* nxtVT = nxtAT + 64 * 128;
    int nt = (ib + 1) & 31;                       // last iter refills tile 0 (harmless)

    // issue next tile's async loads (1-deep pipeline; latency hides under compute)
    if (w < 4) {
      const u16* qb = Qtn + (size_t)nt * (64 * DMODEL);
#pragma unroll
      for (int i = 0; i < 4; ++i)
        gload16(qb + qoff[i], nxtAT + ((w & 3) * 4 + i) * 512);
    } else {
      const u16* vb = Vn + nt * 64;
#pragma unroll
      for (int i = 0; i < 4; ++i)
        gload16(vb + voff[i], nxtVT + ((w & 3) * 4 + i) * 512);
    }

    // QK^T: C[i (2x32 tiles), j(32)]
    f32x16 c0 = fzero16(), c1 = fzero16();
#pragma unroll
    for (int dc = 0; dc < 8; ++dc) {
      short8v a0 = ld_at(curAT, lj, 2 * dc + g);
      short8v a1 = ld_at(curAT, 32 + lj, 2 * dc + g);
      c0 = mfma_bf16(a0, bq[dc], c0);
      c1 = mfma_bf16(a1, bq[dc], c1);
    }

    // online softmax over i for column j = lj (state dup on lane pair l, l^32)
    float mx = -1e30f;
#pragma unroll
    for (int r = 0; r < 16; ++r) { c0[r] *= SC; mx = fmaxf(mx, c0[r]); }
#pragma unroll
    for (int r = 0; r < 16; ++r) { c1[r] *= SC; mx = fmaxf(mx, c1[r]); }
    mx = fmaxf(mx, __shfl_xor(mx, 32, 64));

    // defer-max (T13): skip rescale while max grows < 8 (P bounded by 2^8)
    if (!__all(mx <= m_run + 8.f)) {
      float mn = fmaxf(m_run, mx);
      float al = fast_exp2(m_run - mn);
      m_run = mn;
      l_run *= al;
#pragma unroll
      for (int r = 0; r < 16; ++r) { o0[r] *= al; o1[r] *= al; o2[r] *= al; o3[r] *= al; }
    }
    float ps = 0.f;
#pragma unroll
    for (int r = 0; r < 16; ++r) { c0[r] = fast_exp2(c0[r] - m_run); ps += c0[r]; }
#pragma unroll
    for (int r = 0; r < 16; ++r) { c1[r] = fast_exp2(c1[r] - m_run); ps += c1[r]; }
    ps += __shfl_xor(ps, 32, 64);
    l_run += ps;

    // PV in two halves (keeps pk/ok at 8 regs each): kc0,1 from c0; kc2,3 from c1
    u32 pk[8], ok[8];
#pragma unroll
    for (int half = 0; half < 2; ++half) {
#pragma unroll
      for (int q = 0; q < 4; ++q) {
#pragma unroll
        for (int h = 0; h < 2; ++h) {
          float va = half ? c1[q * 4 + 2 * h]     : c0[q * 4 + 2 * h];
          float vb = half ? c1[q * 4 + 2 * h + 1] : c0[q * 4 + 2 * h + 1];
          pk[q * 2 + h] = packbf(va, vb);
        }
      }
#pragma unroll
      for (int i = 0; i < 8; ++i) ok[i] = __shfl_xor(pk[i], 32, 64);
#pragma unroll
      for (int kh = 0; kh < 2; ++kh) {
        int kc = half * 2 + kh;
        const int base = 4 * kh;
        u32 w0 = g ? ok[base + 2] : pk[base + 0];
        u32 w1 = g ? ok[base + 3] : pk[base + 1];
        u32 w2 = g ? pk[base + 2] : ok[base + 0];
        u32 w3 = g ? pk[base + 3] : ok[base + 1];
        u32x4 uu = {w0, w1, w2, w3};
        short8v pf = __builtin_bit_cast(short8v, uu);
        short8v v0 = ld_vt(curVT, lj,      2 * kc + g);
        short8v v1 = ld_vt(curVT, 32 + lj, 2 * kc + g);
        short8v v2 = ld_vt(curVT, 64 + lj, 2 * kc + g);
        short8v v3 = ld_vt(curVT, 96 + lj, 2 * kc + g);
        o0 = mfma_bf16(v0, pf, o0);
        o1 = mfma_bf16(v1, pf, o1);
        o2 = mfma_bf16(v2, pf, o2);
        o3 = mfma_bf16(v3, pf, o3);
      }
    }
    __syncthreads();   // drains own vmcnt -> next tile staged & visible
  }

  // epilogue: O /= l, store bf16 to Ows[n][j][d]
  float inv = 1.f / l_run;
  int jme = j0 + w * 32 + lj;
  u16* obase = Ows + ((size_t)n * SEQ + jme) * DMODEL;

#define STORE_OT(OV, DT)                                                  \
  {                                                                       \
    _Pragma("unroll") for (int q = 0; q < 4; ++q) {                       \
      int d0 = (DT) * 32 + 4 * g + 8 * q;                                 \
      u32x2 val;                                                          \
      val.x = bfpair(OV[4 * q + 0] * inv, OV[4 * q + 1] * inv);           \
      val.y = bfpair(OV[4 * q + 2] * inv, OV[4 * q + 3] * inv);           \
      *reinterpret_cast<u32x2*>(obase + d0) = val;                        \
    }                                                                     \
  }
  STORE_OT(o0, 0) STORE_OT(o1, 1) STORE_OT(o2, 2) STORE_OT(o3, 3)
#undef STORE_OT
}

// ---------- projection out[b][dm][j] = sum_c Wt[dm][c] * Ows[b,c][j] ----------
__global__ __launch_bounds__(256) void proj_kernel(
    const u16* __restrict__ Ows, const u16* __restrict__ Wt, float* __restrict__ out) {
  __shared__ __align__(16) u16 BT[32 * 128];
  const int tid = threadIdx.x;
  const int w = tid >> 6, lane = tid & 63, g = lane >> 5, lj = lane & 31;
  const int b = blockIdx.x >> 6;
  const int j0 = (blockIdx.x & 63) * 32;
  f32x16 acc = fzero16();
#pragma unroll 1
  for (int h = 0; h < 16; ++h) {
    __syncthreads();
#pragma unroll
    for (int rr = 0; rr < 2; ++rr) {
      int s = tid + rr * 256;
      int r = s >> 4, cc = s & 15;
      u16x8 v = *reinterpret_cast<const u16x8*>(
          Ows + ((size_t)(b * 16 + h) * SEQ + j0 + r) * DMODEL + cc * 8);
      *reinterpret_cast<u16x8*>(BT + r * 128 + ((cc ^ (r & 7)) * 8)) = v;
    }
    __syncthreads();
#pragma unroll
    for (int kc = 0; kc < 8; ++kc) {
      short8v a = *reinterpret_cast<const short8v*>(
          Wt + (size_t)(w * 32 + lj) * SEQ + h * 128 + kc * 16 + g * 8);
      short8v bb = *reinterpret_cast<const short8v*>(
          BT + lj * 128 + (((2 * kc + g) ^ (lj & 7)) * 8));
      acc = mfma_bf16(a, bb, acc);
    }
  }
#pragma unroll
  for (int q = 0; q < 4; ++q) {
#pragma unroll
    for (int r = 0; r < 4; ++r) {
      int dm = w * 32 + 4 * g + 8 * q + r;
      out[((size_t)b * DMODEL + dm) * SEQ + j0 + lj] = acc[4 * q + r];
    }
  }
}

// ---------- host launcher ----------
extern "C" void kernel_launch(void* const* d_in, const int* in_sizes, int n_in,
                              void* d_out, int out_size, void* d_ws, size_t ws_size,
                              hipStream_t stream) {
  (void)in_sizes; (void)n_in; (void)out_size; (void)ws_size;
  const float* Q = (const float*)d_in[1];
  const float* K = (const float*)d_in[2];
  const float* V = (const float*)d_in[3];
  const float* W = (const float*)d_in[4];
  const size_t NEL = (size_t)HEADS * SEQ * DMODEL;   // 16.8M elements
  u16* Qt  = (u16*)d_ws;                 // 33.5 MB
  u16* V16 = Qt + NEL;                   // 33.5 MB
  u16* Ows = V16 + NEL;                  // 33.5 MB
  u16* Wt  = Ows + NEL;                  // 0.5 MB
  float* out = (float*)d_out;

  prep_qt<<<dim3(2048), dim3(256), 0, stream>>>(Q, Qt);
  prep_v<<<dim3(8192), dim3(256), 0, stream>>>(V, V16);
  wtrans_kernel<<<dim3(512), dim3(256), 0, stream>>>(W, Wt);
  attn_kernel<<<dim3(512), dim3(512), 0, stream>>>(Qt, K, V16, Ows);
  proj_kernel<<<dim3(256), dim3(256), 0, stream>>>(Ows, Wt, out);
}

// Round 4
// 247.986 us; speedup vs baseline: 1.5851x; 1.5851x over previous
//
#include <hip/hip_runtime.h>
#include <hip/hip_bf16.h>

typedef unsigned short u16;
typedef unsigned int   u32;
typedef short  short8v __attribute__((ext_vector_type(8)));
typedef u16    u16x8   __attribute__((ext_vector_type(8)));
typedef float  f32x16  __attribute__((ext_vector_type(16)));
typedef float  f32x4v  __attribute__((ext_vector_type(4)));
typedef u32    u32x2   __attribute__((ext_vector_type(2)));
typedef u32    u32x4   __attribute__((ext_vector_type(4)));

#define HEADS 64
#define DMODEL 128
#define SEQ 2048

// ---------- helpers ----------

__device__ __forceinline__ f32x16 mfma_bf16(short8v a, short8v b, f32x16 c) {
  return __builtin_amdgcn_mfma_f32_32x32x16_bf16(a, b, c, 0, 0, 0);
}

__device__ __forceinline__ f32x16 fzero16() {
  f32x16 z;
#pragma unroll
  for (int i = 0; i < 16; ++i) z[i] = 0.f;
  return z;
}

__device__ __forceinline__ float fast_exp2(float x) {
  float r;
  asm("v_exp_f32 %0, %1" : "=v"(r) : "v"(x));   // v_exp_f32 IS exp2
  return r;
}

// round-to-nearest-even f32 -> bf16 bits
__device__ __forceinline__ u32 bfround(float x) {
  u32 u = __builtin_bit_cast(u32, x);
  u += 0x7fffu + ((u >> 16) & 1u);
  return u >> 16;
}
__device__ __forceinline__ u32 bfpair(float lo, float hi) {
  u32 a = __builtin_bit_cast(u32, lo); a += 0x7fffu + ((a >> 16) & 1u);
  u32 b = __builtin_bit_cast(u32, hi); b += 0x7fffu + ((b >> 16) & 1u);
  return (a >> 16) | (b & 0xffff0000u);
}
// hot-loop pack -> v_cvt_pk_bf16_f32 via compiler (m240)
__device__ __forceinline__ u32 packbf(float lo, float hi) {
  u32 l16 = (u32)__builtin_bit_cast(u16, __float2bfloat16(lo));
  u32 h16 = (u32)__builtin_bit_cast(u16, __float2bfloat16(hi));
  return l16 | (h16 << 16);
}

// async global->LDS, 16B/lane, dest = wave-uniform base + lane*16
typedef const __attribute__((address_space(1))) void* gp1_t;
typedef __attribute__((address_space(3))) void* lp3_t;
__device__ __forceinline__ void gload16(const u16* g, u16* l) {
  __builtin_amdgcn_global_load_lds((gp1_t)g, (lp3_t)l, 16, 0, 0);
}

// counted-vmcnt barrier (T4): tile issued LAST iter is complete; the 4
// just-issued loads stay in flight across the barrier.
#define PIPE_BARRIER()                                        \
  do {                                                        \
    asm volatile("s_waitcnt vmcnt(4)" ::: "memory");          \
    __builtin_amdgcn_sched_barrier(0);                        \
    __builtin_amdgcn_s_barrier();                             \
    __builtin_amdgcn_sched_barrier(0);                        \
  } while (0)

// K-prologue transposing stage: src [128 d][2048 pos] f32 ->
// LDS tile [64 pos][128 d] bf16, chunk' = chunk ^ (row & 15)  (4-bit swizzle)
__device__ __forceinline__ void stage_T(const float* __restrict__ src, int pos0,
                                        u16* lds, int tid) {
  int ic = tid & 7;
  int d0 = (tid >> 3) * 2;
  const float* p = src + d0 * SEQ + pos0 + ic * 8;
  f32x4v xa = *reinterpret_cast<const f32x4v*>(p);
  f32x4v xb = *reinterpret_cast<const f32x4v*>(p + 4);
  f32x4v ya = *reinterpret_cast<const f32x4v*>(p + SEQ);
  f32x4v yb = *reinterpret_cast<const f32x4v*>(p + SEQ + 4);
  u32* lds32 = reinterpret_cast<u32*>(lds);
  int cc = d0 >> 3;
#pragma unroll
  for (int k = 0; k < 8; ++k) {
    int r = ic * 8 + k;
    int c2 = cc ^ (r & 15);
    float xv = (k < 4) ? xa[k & 3] : xb[k & 3];
    float yv = (k < 4) ? ya[k & 3] : yb[k & 3];
    lds32[(r * 128 + c2 * 8 + (d0 & 7)) >> 1] = bfpair(xv, yv);
  }
}

// fragment reads (ds_read_b128), undoing the XOR swizzles
__device__ __forceinline__ short8v ld_at(const u16* lds, int row, int chunk) {
  return *reinterpret_cast<const short8v*>(lds + row * 128 + ((chunk ^ (row & 15)) * 8));
}
__device__ __forceinline__ short8v ld_vt(const u16* lds, int d, int chunk) {
  return *reinterpret_cast<const short8v*>(lds + d * 64 + ((chunk ^ (d & 7)) * 8));
}

// ---------- prep kernels ----------

// Q f32 [n][128 d][2048 s] -> Qt bf16 [n][2048 s][128 d]
__global__ __launch_bounds__(256) void prep_qt(const float* __restrict__ Q,
                                               u16* __restrict__ Qt) {
  int blk = blockIdx.x;            // 64 heads * 32 pos-tiles
  int n = blk >> 5, pt = blk & 31;
  const float* src = Q + (size_t)n * DMODEL * SEQ;
  u16* dst = Qt + (size_t)n * SEQ * DMODEL + (size_t)pt * 64 * DMODEL;
  int t = threadIdx.x;
  int pq = t & 15, dq = t >> 4;
#pragma unroll
  for (int p = 0; p < 2; ++p) {
    int d0 = (dq + 16 * p) * 4;
    const float* s0 = src + (size_t)d0 * SEQ + pt * 64 + pq * 4;
    f32x4v r0 = *reinterpret_cast<const f32x4v*>(s0);
    f32x4v r1 = *reinterpret_cast<const f32x4v*>(s0 + SEQ);
    f32x4v r2 = *reinterpret_cast<const f32x4v*>(s0 + 2 * SEQ);
    f32x4v r3 = *reinterpret_cast<const f32x4v*>(s0 + 3 * SEQ);
#pragma unroll
    for (int j = 0; j < 4; ++j) {
      u32x2 v = { bfpair(r0[j], r1[j]), bfpair(r2[j], r3[j]) };
      *reinterpret_cast<u32x2*>(dst + (pq * 4 + j) * DMODEL + d0) = v;
    }
  }
}

// V f32 [n][128 d][2048 s] -> tile-contiguous bf16 [n][it(32)][128 d][64 s]
__global__ __launch_bounds__(256) void prep_v(const float* __restrict__ V,
                                              u16* __restrict__ V16t) {
  int blk = blockIdx.x;            // n*32 + it
  int n = blk >> 5, it = blk & 31;
  int t = threadIdx.x;
  int s8 = (t & 7) * 8;
  const float* src = V + (size_t)n * DMODEL * SEQ + it * 64 + s8;
  u16* dst = V16t + (size_t)blk * DMODEL * 64 + s8;
#pragma unroll
  for (int rr = 0; rr < 4; ++rr) {
    int d = (t >> 3) + 32 * rr;
    const float* p = src + (size_t)d * SEQ;
    f32x4v a = *reinterpret_cast<const f32x4v*>(p);
    f32x4v b = *reinterpret_cast<const f32x4v*>(p + 4);
    u32x4 v = { bfpair(a[0], a[1]), bfpair(a[2], a[3]),
                bfpair(b[0], b[1]), bfpair(b[2], b[3]) };
    *reinterpret_cast<u32x4*>(dst + d * 64) = v;
  }
}

// W transpose (f32 [2048][128] -> bf16 [128][2048])
__global__ void wtrans_kernel(const float* __restrict__ Wsrc, u16* __restrict__ Wt) {
  int e = blockIdx.x * 256 + threadIdx.x;
#pragma unroll
  for (int rr = 0; rr < 2; ++rr) {
    int o = e + rr * 131072;
    int dm = o >> 11, c = o & 2047;
    Wt[o] = (u16)bfround(Wsrc[c * 128 + dm]);
  }
}

// ---------- flash attention (softmax over i, per column j) ----------
// 512 blocks = head(64) x jblock(8 x 256 j), head%8 -> XCD. 8 waves, 32 j/wave.
// LDS: 3 buffers x 32KB (AT[64 pos][128 d] + VT[128 d][64 i]), 2-deep prefetch.
#define BUFW (64 * 128 + 128 * 64)   // u16 per buffer (32KB)

__global__ __launch_bounds__(512, 2) void attn_kernel(
    const u16* __restrict__ Qt, const float* __restrict__ K,
    const u16* __restrict__ V16t, u16* __restrict__ Ows) {
  __shared__ __align__(16) u16 LDSb[3 * BUFW];   // 96KB
  const int tid = threadIdx.x;
  const int w = tid >> 6;
  const int lane = tid & 63;
  const int g = lane >> 5;
  const int lj = lane & 31;
  const int p_ = blockIdx.x;
  const int n = ((p_ >> 6) << 3) | (p_ & 7);
  const int j0 = ((p_ >> 3) & 7) * 256;
  const u16* Qtn = Qt + (size_t)n * SEQ * DMODEL;
  const float* Kb = K + (size_t)n * DMODEL * SEQ;
  const u16* Vtn = V16t + (size_t)n * 32 * DMODEL * 64;

  // staging lane constants (4 gload16 per wave per tile)
  // waves 0-3: Q-tile; inst idx = (w&3)*4+i -> pos = idx*4 + (lane>>4)
  // waves 4-7: V-tile; inst idx -> d = idx*8 + (lane>>3); tiles are 16KB contiguous
  int qoff[4], voff[4];
#pragma unroll
  for (int i = 0; i < 4; ++i) {
    int idx = (w & 3) * 4 + i;
    int pos = idx * 4 + (lane >> 4);
    qoff[i] = pos * DMODEL + (((lane & 15) ^ (pos & 15)) * 8);
    int d = idx * 8 + (lane >> 3);
    voff[i] = d * 64 + (((lane & 7) ^ (d & 7)) * 8);
  }

#define ISSUE_TILE(tile, buf)                                              \
  {                                                                        \
    if (w < 4) {                                                           \
      const u16* qb = Qtn + (size_t)(tile) * (64 * DMODEL);                \
      _Pragma("unroll") for (int i = 0; i < 4; ++i)                        \
          gload16(qb + qoff[i], (buf) + ((w & 3) * 4 + i) * 512);          \
    } else {                                                               \
      const u16* vb = Vtn + (size_t)(tile) * (DMODEL * 64);                \
      _Pragma("unroll") for (int i = 0; i < 4; ++i)                        \
          gload16(vb + voff[i], (buf) + 64 * DMODEL + ((w & 3) * 4 + i) * 512); \
    }                                                                      \
  }

  // kick off tiles 0,1 into buffers 0,1 (prologue __syncthreads drains them)
  ISSUE_TILE(0, LDSb);
  ISSUE_TILE(1, LDSb + BUFW);

  // --- K prologue: this wave's 32 K-rows (j) into registers (buf2 scratch) ---
  short8v bq[8];
  u16* KS = LDSb + 2 * BUFW;
#pragma unroll 1
  for (int p = 0; p < 4; ++p) {
    stage_T(Kb, j0 + p * 64, KS, tid);
    __syncthreads();
    if ((w >> 1) == p) {
      int row = (w & 1) * 32 + lj;
#pragma unroll
      for (int c = 0; c < 8; ++c) bq[c] = ld_at(KS, row, 2 * c + g);
    }
    __syncthreads();
  }

  f32x16 o0 = fzero16(), o1 = fzero16(), o2 = fzero16(), o3 = fzero16();
  float m_run = -1e30f, l_run = 0.f;
  const float SC = (float)(1.4426950408889634 / 11.313708498984761); // log2e/sqrt(128)

  int cidx = 0;
#pragma unroll 1
  for (int ib = 0; ib < 32; ++ib) {
    u16* curAT = LDSb + cidx * BUFW;
    u16* curVT = curAT + 64 * DMODEL;
    int widx = cidx + 2; if (widx >= 3) widx -= 3;
    u16* nxt = LDSb + widx * BUFW;
    cidx = (cidx >= 2) ? 0 : cidx + 1;

    // issue tile ib+2 (wrapped; keeps outstanding-count uniform for vmcnt(4))
    ISSUE_TILE((ib + 2) & 31, nxt);

    // QK^T: C[i (2x32 tiles), j(32)]
    f32x16 c0 = fzero16(), c1 = fzero16();
    __builtin_amdgcn_s_setprio(1);
#pragma unroll
    for (int dc = 0; dc < 8; ++dc) {
      short8v a0 = ld_at(curAT, lj, 2 * dc + g);
      short8v a1 = ld_at(curAT, 32 + lj, 2 * dc + g);
      c0 = mfma_bf16(a0, bq[dc], c0);
      c1 = mfma_bf16(a1, bq[dc], c1);
    }
    __builtin_amdgcn_s_setprio(0);

    // online softmax over i for column j = lj (state dup on lanes l, l^32)
    float mx = -1e30f;
#pragma unroll
    for (int r = 0; r < 16; ++r) { c0[r] *= SC; mx = fmaxf(mx, c0[r]); }
#pragma unroll
    for (int r = 0; r < 16; ++r) { c1[r] *= SC; mx = fmaxf(mx, c1[r]); }
    mx = fmaxf(mx, __shfl_xor(mx, 32, 64));

    // defer-max (T13): skip rescale while max grows < 8
    if (!__all(mx <= m_run + 8.f)) {
      float mn = fmaxf(m_run, mx);
      float al = fast_exp2(m_run - mn);
      m_run = mn;
      l_run *= al;
#pragma unroll
      for (int r = 0; r < 16; ++r) { o0[r] *= al; o1[r] *= al; o2[r] *= al; o3[r] *= al; }
    }
    float ps = 0.f;
#pragma unroll
    for (int r = 0; r < 16; ++r) { c0[r] = fast_exp2(c0[r] - m_run); ps += c0[r]; }
#pragma unroll
    for (int r = 0; r < 16; ++r) { c1[r] = fast_exp2(c1[r] - m_run); ps += c1[r]; }
    ps += __shfl_xor(ps, 32, 64);
    l_run += ps;

    // PV in two halves: kc0,1 from c0; kc2,3 from c1
    u32 pk[8], ok[8];
#pragma unroll
    for (int half = 0; half < 2; ++half) {
#pragma unroll
      for (int q = 0; q < 4; ++q) {
#pragma unroll
        for (int h = 0; h < 2; ++h) {
          float va = half ? c1[q * 4 + 2 * h]     : c0[q * 4 + 2 * h];
          float vb = half ? c1[q * 4 + 2 * h + 1] : c0[q * 4 + 2 * h + 1];
          pk[q * 2 + h] = packbf(va, vb);
        }
      }
#pragma unroll
      for (int i = 0; i < 8; ++i) ok[i] = __shfl_xor(pk[i], 32, 64);
      __builtin_amdgcn_s_setprio(1);
#pragma unroll
      for (int kh = 0; kh < 2; ++kh) {
        int kc = half * 2 + kh;
        const int base = 4 * kh;
        u32 w0 = g ? ok[base + 2] : pk[base + 0];
        u32 w1 = g ? ok[base + 3] : pk[base + 1];
        u32 w2 = g ? pk[base + 2] : ok[base + 0];
        u32 w3 = g ? pk[base + 3] : ok[base + 1];
        u32x4 uu = {w0, w1, w2, w3};
        short8v pf = __builtin_bit_cast(short8v, uu);
        short8v v0 = ld_vt(curVT, lj,      2 * kc + g);
        short8v v1 = ld_vt(curVT, 32 + lj, 2 * kc + g);
        short8v v2 = ld_vt(curVT, 64 + lj, 2 * kc + g);
        short8v v3 = ld_vt(curVT, 96 + lj, 2 * kc + g);
        o0 = mfma_bf16(v0, pf, o0);
        o1 = mfma_bf16(v1, pf, o1);
        o2 = mfma_bf16(v2, pf, o2);
        o3 = mfma_bf16(v3, pf, o3);
      }
      __builtin_amdgcn_s_setprio(0);
    }
    PIPE_BARRIER();   // tile ib+1 complete; tile ib+2's 4 loads stay in flight
  }

  // epilogue: O /= l, store bf16 to Ows[n][j][d] (L2 write-combines the 8B stores)
  float inv = 1.f / l_run;
  int jme = j0 + w * 32 + lj;
  u16* obase = Ows + ((size_t)n * SEQ + jme) * DMODEL;

#define STORE_OT(OV, DT)                                                  \
  {                                                                       \
    _Pragma("unroll") for (int q = 0; q < 4; ++q) {                       \
      int d0 = (DT) * 32 + 4 * g + 8 * q;                                 \
      u32x2 val;                                                          \
      val.x = bfpair(OV[4 * q + 0] * inv, OV[4 * q + 1] * inv);           \
      val.y = bfpair(OV[4 * q + 2] * inv, OV[4 * q + 3] * inv);           \
      *reinterpret_cast<u32x2*>(obase + d0) = val;                        \
    }                                                                     \
  }
  STORE_OT(o0, 0) STORE_OT(o1, 1) STORE_OT(o2, 2) STORE_OT(o3, 3)
#undef STORE_OT
#undef ISSUE_TILE
}

// ---------- projection out[b][dm][j] = sum_c Wt[dm][c] * Ows[b,c][j] ----------
__global__ __launch_bounds__(256) void proj_kernel(
    const u16* __restrict__ Ows, const u16* __restrict__ Wt, float* __restrict__ out) {
  __shared__ __align__(16) u16 BT[32 * 128];
  const int tid = threadIdx.x;
  const int w = tid >> 6, lane = tid & 63, g = lane >> 5, lj = lane & 31;
  const int b = blockIdx.x >> 6;
  const int j0 = (blockIdx.x & 63) * 32;
  f32x16 acc = fzero16();
#pragma unroll 1
  for (int h = 0; h < 16; ++h) {
    __syncthreads();
#pragma unroll
    for (int rr = 0; rr < 2; ++rr) {
      int s = tid + rr * 256;
      int r = s >> 4, cc = s & 15;
      u16x8 v = *reinterpret_cast<const u16x8*>(
          Ows + ((size_t)(b * 16 + h) * SEQ + j0 + r) * DMODEL + cc * 8);
      *reinterpret_cast<u16x8*>(BT + r * 128 + ((cc ^ (r & 7)) * 8)) = v;
    }
    __syncthreads();
#pragma unroll
    for (int kc = 0; kc < 8; ++kc) {
      short8v a = *reinterpret_cast<const short8v*>(
          Wt + (size_t)(w * 32 + lj) * SEQ + h * 128 + kc * 16 + g * 8);
      short8v bb = *reinterpret_cast<const short8v*>(
          BT + lj * 128 + (((2 * kc + g) ^ (lj & 7)) * 8));
      acc = mfma_bf16(a, bb, acc);
    }
  }
#pragma unroll
  for (int q = 0; q < 4; ++q) {
#pragma unroll
    for (int r = 0; r < 4; ++r) {
      int dm = w * 32 + 4 * g + 8 * q + r;
      out[((size_t)b * DMODEL + dm) * SEQ + j0 + lj] = acc[4 * q + r];
    }
  }
}

// ---------- host launcher ----------
extern "C" void kernel_launch(void* const* d_in, const int* in_sizes, int n_in,
                              void* d_out, int out_size, void* d_ws, size_t ws_size,
                              hipStream_t stream) {
  (void)in_sizes; (void)n_in; (void)out_size; (void)ws_size;
  const float* Q = (const float*)d_in[1];
  const float* K = (const float*)d_in[2];
  const float* V = (const float*)d_in[3];
  const float* W = (const float*)d_in[4];
  const size_t NEL = (size_t)HEADS * SEQ * DMODEL;   // 16.8M elements
  u16* Qt   = (u16*)d_ws;                // 33.5 MB
  u16* V16t = Qt + NEL;                  // 33.5 MB (tile-contiguous)
  u16* Ows  = V16t + NEL;                // 33.5 MB
  u16* Wt   = Ows + NEL;                 // 0.5 MB
  float* out = (float*)d_out;

  prep_qt<<<dim3(2048), dim3(256), 0, stream>>>(Q, Qt);
  prep_v<<<dim3(2048), dim3(256), 0, stream>>>(V, V16t);
  wtrans_kernel<<<dim3(512), dim3(256), 0, stream>>>(W, Wt);
  attn_kernel<<<dim3(512), dim3(512), 0, stream>>>(Qt, K, V16t, Ows);
  proj_kernel<<<dim3(256), dim3(256), 0, stream>>>(Ows, Wt, out);
}

// Round 5
// 243.077 us; speedup vs baseline: 1.6171x; 1.0202x over previous
//
#include <hip/hip_runtime.h>
#include <hip/hip_bf16.h>

typedef unsigned short u16;
typedef unsigned int   u32;
typedef short  short8v __attribute__((ext_vector_type(8)));
typedef u16    u16x8   __attribute__((ext_vector_type(8)));
typedef float  f32x16  __attribute__((ext_vector_type(16)));
typedef float  f32x4v  __attribute__((ext_vector_type(4)));
typedef u32    u32x2   __attribute__((ext_vector_type(2)));
typedef u32    u32x4   __attribute__((ext_vector_type(4)));

#define HEADS 64
#define DMODEL 128
#define SEQ 2048

// log2(e)/sqrt(128), folded into Qt during prep
#define SCQ 0.1275293f

// ---------- helpers ----------

__device__ __forceinline__ f32x16 mfma_bf16(short8v a, short8v b, f32x16 c) {
  return __builtin_amdgcn_mfma_f32_32x32x16_bf16(a, b, c, 0, 0, 0);
}

__device__ __forceinline__ f32x16 fzero16() {
  f32x16 z;
#pragma unroll
  for (int i = 0; i < 16; ++i) z[i] = 0.f;
  return z;
}

__device__ __forceinline__ float fast_exp2(float x) {
  float r;
  asm("v_exp_f32 %0, %1" : "=v"(r) : "v"(x));   // v_exp_f32 IS exp2
  return r;
}

// round-to-nearest-even f32 -> bf16 bits
__device__ __forceinline__ u32 bfround(float x) {
  u32 u = __builtin_bit_cast(u32, x);
  u += 0x7fffu + ((u >> 16) & 1u);
  return u >> 16;
}
__device__ __forceinline__ u32 bfpair(float lo, float hi) {
  u32 a = __builtin_bit_cast(u32, lo); a += 0x7fffu + ((a >> 16) & 1u);
  u32 b = __builtin_bit_cast(u32, hi); b += 0x7fffu + ((b >> 16) & 1u);
  return (a >> 16) | (b & 0xffff0000u);
}
// hot-loop pack -> v_cvt_pk_bf16_f32 via compiler (m240)
__device__ __forceinline__ u32 packbf(float lo, float hi) {
  u32 l16 = (u32)__builtin_bit_cast(u16, __float2bfloat16(lo));
  u32 h16 = (u32)__builtin_bit_cast(u16, __float2bfloat16(hi));
  return l16 | (h16 << 16);
}

// async global->LDS, 16B/lane, dest = wave-uniform base + lane*16
typedef const __attribute__((address_space(1))) void* gp1_t;
typedef __attribute__((address_space(3))) void* lp3_t;
__device__ __forceinline__ void gload16(const u16* g, u16* l) {
  __builtin_amdgcn_global_load_lds((gp1_t)g, (lp3_t)l, 16, 0, 0);
}

// K-prologue transposing stage: src [128 d][2048 pos] f32 ->
// LDS tile [64 pos][128 d] bf16, chunk' = chunk ^ (row & 15)
__device__ __forceinline__ void stage_T(const float* __restrict__ src, int pos0,
                                        u16* lds, int tid) {
  int ic = tid & 7;
  int d0 = (tid >> 3) * 2;
  const float* p = src + d0 * SEQ + pos0 + ic * 8;
  f32x4v xa = *reinterpret_cast<const f32x4v*>(p);
  f32x4v xb = *reinterpret_cast<const f32x4v*>(p + 4);
  f32x4v ya = *reinterpret_cast<const f32x4v*>(p + SEQ);
  f32x4v yb = *reinterpret_cast<const f32x4v*>(p + SEQ + 4);
  u32* lds32 = reinterpret_cast<u32*>(lds);
  int cc = d0 >> 3;
#pragma unroll
  for (int k = 0; k < 8; ++k) {
    int r = ic * 8 + k;
    int c2 = cc ^ (r & 15);
    float xv = (k < 4) ? xa[k & 3] : xb[k & 3];
    float yv = (k < 4) ? ya[k & 3] : yb[k & 3];
    lds32[(r * 128 + c2 * 8 + (d0 & 7)) >> 1] = bfpair(xv, yv);
  }
}

// fragment reads (ds_read_b128), undoing the XOR swizzles
__device__ __forceinline__ short8v ld_at(const u16* lds, int row, int chunk) {
  return *reinterpret_cast<const short8v*>(lds + row * 128 + ((chunk ^ (row & 15)) * 8));
}
__device__ __forceinline__ short8v ld_vt(const u16* lds, int d, int chunk) {
  return *reinterpret_cast<const short8v*>(lds + d * 64 + ((chunk ^ (d & 7)) * 8));
}

// ---------- prep kernels ----------

// Q f32 [n][128 d][2048 s] -> Qt bf16 [n][2048 s][128 d], scaled by SCQ
__global__ __launch_bounds__(256) void prep_qt(const float* __restrict__ Q,
                                               u16* __restrict__ Qt) {
  int blk = blockIdx.x;            // 64 heads * 32 pos-tiles
  int n = blk >> 5, pt = blk & 31;
  const float* src = Q + (size_t)n * DMODEL * SEQ;
  u16* dst = Qt + (size_t)n * SEQ * DMODEL + (size_t)pt * 64 * DMODEL;
  int t = threadIdx.x;
  int pq = t & 15, dq = t >> 4;
#pragma unroll
  for (int p = 0; p < 2; ++p) {
    int d0 = (dq + 16 * p) * 4;
    const float* s0 = src + (size_t)d0 * SEQ + pt * 64 + pq * 4;
    f32x4v r0 = *reinterpret_cast<const f32x4v*>(s0);
    f32x4v r1 = *reinterpret_cast<const f32x4v*>(s0 + SEQ);
    f32x4v r2 = *reinterpret_cast<const f32x4v*>(s0 + 2 * SEQ);
    f32x4v r3 = *reinterpret_cast<const f32x4v*>(s0 + 3 * SEQ);
#pragma unroll
    for (int j = 0; j < 4; ++j) {
      u32x2 v = { bfpair(r0[j] * SCQ, r1[j] * SCQ), bfpair(r2[j] * SCQ, r3[j] * SCQ) };
      *reinterpret_cast<u32x2*>(dst + (pq * 4 + j) * DMODEL + d0) = v;
    }
  }
}

// V f32 [n][128 d][2048 s] -> tile-contiguous bf16 [n][it(32)][128 d][64 s]
__global__ __launch_bounds__(256) void prep_v(const float* __restrict__ V,
                                              u16* __restrict__ V16t) {
  int blk = blockIdx.x;            // n*32 + it
  int n = blk >> 5, it = blk & 31;
  int t = threadIdx.x;
  int s8 = (t & 7) * 8;
  const float* src = V + (size_t)n * DMODEL * SEQ + it * 64 + s8;
  u16* dst = V16t + (size_t)blk * DMODEL * 64 + s8;
#pragma unroll
  for (int rr = 0; rr < 4; ++rr) {
    int d = (t >> 3) + 32 * rr;
    const float* p = src + (size_t)d * SEQ;
    f32x4v a = *reinterpret_cast<const f32x4v*>(p);
    f32x4v b = *reinterpret_cast<const f32x4v*>(p + 4);
    u32x4 v = { bfpair(a[0], a[1]), bfpair(a[2], a[3]),
                bfpair(b[0], b[1]), bfpair(b[2], b[3]) };
    *reinterpret_cast<u32x4*>(dst + d * 64) = v;
  }
}

// W transpose (f32 [2048][128] -> bf16 [128][2048])
__global__ void wtrans_kernel(const float* __restrict__ Wsrc, u16* __restrict__ Wt) {
  int e = blockIdx.x * 256 + threadIdx.x;
#pragma unroll
  for (int rr = 0; rr < 2; ++rr) {
    int o = e + rr * 131072;
    int dm = o >> 11, c = o & 2047;
    Wt[o] = (u16)bfround(Wsrc[c * 128 + dm]);
  }
}

// ---------- flash attention (softmax over i, per column j) ----------
// 512 blocks = head(64) x jblock(8 x 256 j), head%8 -> XCD. 8 waves, 32 j/wave.
// LDS: 4 buffers x 32KB (pairs); superstep = 2 tiles per barrier.
#define BUFW (64 * 128 + 128 * 64)   // u16 per buffer (32KB)

__global__ __launch_bounds__(512, 2) void attn_kernel(
    const u16* __restrict__ Qt, const float* __restrict__ K,
    const u16* __restrict__ V16t, u16* __restrict__ Ows) {
  __shared__ __align__(16) u16 LDSb[4 * BUFW];   // 128KB
  const int tid = threadIdx.x;
  const int w = tid >> 6;
  const int lane = tid & 63;
  const int g = lane >> 5;
  const int lj = lane & 31;
  const int p_ = blockIdx.x;
  const int n = ((p_ >> 6) << 3) | (p_ & 7);
  const int j0 = ((p_ >> 3) & 7) * 256;
  const u16* Qtn = Qt + (size_t)n * SEQ * DMODEL;
  const float* Kb = K + (size_t)n * DMODEL * SEQ;
  const u16* Vtn = V16t + (size_t)n * 32 * DMODEL * 64;

  // staging lane constants (4 gload16 per wave per tile)
  int qoff[4], voff[4];
#pragma unroll
  for (int i = 0; i < 4; ++i) {
    int idx = (w & 3) * 4 + i;
    int pos = idx * 4 + (lane >> 4);
    qoff[i] = pos * DMODEL + (((lane & 15) ^ (pos & 15)) * 8);
    int d = idx * 8 + (lane >> 3);
    voff[i] = d * 64 + (((lane & 7) ^ (d & 7)) * 8);
  }

#define ISSUE_TILE(tile, buf)                                              \
  {                                                                        \
    if (w < 4) {                                                           \
      const u16* qb = Qtn + (size_t)(tile) * (64 * DMODEL);                \
      _Pragma("unroll") for (int i = 0; i < 4; ++i)                        \
          gload16(qb + qoff[i], (buf) + ((w & 3) * 4 + i) * 512);          \
    } else {                                                               \
      const u16* vb = Vtn + (size_t)(tile) * (DMODEL * 64);                \
      _Pragma("unroll") for (int i = 0; i < 4; ++i)                        \
          gload16(vb + voff[i], (buf) + 64 * DMODEL + ((w & 3) * 4 + i) * 512); \
    }                                                                      \
  }

  // --- K prologue FIRST (uses buf0 area as scratch, before any tile DMA) ---
  short8v bq[8];
#pragma unroll 1
  for (int p = 0; p < 4; ++p) {
    stage_T(Kb, j0 + p * 64, LDSb, tid);
    __syncthreads();
    if ((w >> 1) == p) {
      int row = (w & 1) * 32 + lj;
#pragma unroll
      for (int c = 0; c < 8; ++c) bq[c] = ld_at(LDSb, row, 2 * c + g);
    }
    __syncthreads();
  }

  // prime pair 0 with tiles 0,1
  ISSUE_TILE(0, LDSb);
  ISSUE_TILE(1, LDSb + BUFW);
  asm volatile("s_waitcnt vmcnt(0)" ::: "memory");
  __builtin_amdgcn_s_barrier();

  f32x16 o0 = fzero16(), o1 = fzero16(), o2 = fzero16(), o3 = fzero16();
  float m_run = -1e30f, l_run = 0.f;

#pragma unroll 1
  for (int ss = 0; ss < 16; ++ss) {
    u16* cp = LDSb + (ss & 1) * (2 * BUFW);        // pair being computed
    u16* op = LDSb + ((ss & 1) ^ 1) * (2 * BUFW);  // pair retired at last barrier

    // issue the next superstep's two tiles into the freed pair
    ISSUE_TILE((2 * ss + 2) & 31, op);
    ISSUE_TILE((2 * ss + 3) & 31, op + BUFW);

#pragma unroll
    for (int h = 0; h < 2; ++h) {
      u16* curAT = cp + h * BUFW;
      u16* curVT = curAT + 64 * DMODEL;

      // QK^T: C[i (2x32 tiles), j(32)]  (Qt pre-scaled -> scores in log2 units)
      f32x16 c0 = fzero16(), c1 = fzero16();
      __builtin_amdgcn_s_setprio(1);
#pragma unroll
      for (int dc = 0; dc < 8; ++dc) {
        short8v a0 = ld_at(curAT, lj, 2 * dc + g);
        short8v a1 = ld_at(curAT, 32 + lj, 2 * dc + g);
        c0 = mfma_bf16(a0, bq[dc], c0);
        c1 = mfma_bf16(a1, bq[dc], c1);
      }
      __builtin_amdgcn_s_setprio(0);

      // tree max over the 32 lane-local values, then pair-combine
      float m8[8];
#pragma unroll
      for (int r = 0; r < 8; ++r)
        m8[r] = fmaxf(fmaxf(c0[r], c0[r + 8]), fmaxf(c1[r], c1[r + 8]));
#pragma unroll
      for (int r = 0; r < 4; ++r) m8[r] = fmaxf(m8[r], m8[r + 4]);
      float mx = fmaxf(fmaxf(m8[0], m8[1]), fmaxf(m8[2], m8[3]));
      mx = fmaxf(mx, __shfl_xor(mx, 32, 64));

      // defer-max (T13): skip rescale while max grows < 8 (P bounded by 2^8)
      if (!__all(mx <= m_run + 8.f)) {
        float mn = fmaxf(m_run, mx);
        float al = fast_exp2(m_run - mn);
        m_run = mn;
        l_run *= al;
#pragma unroll
        for (int r = 0; r < 16; ++r) { o0[r] *= al; o1[r] *= al; o2[r] *= al; o3[r] *= al; }
      }
#pragma unroll
      for (int r = 0; r < 16; ++r) c0[r] = fast_exp2(c0[r] - m_run);
#pragma unroll
      for (int r = 0; r < 16; ++r) c1[r] = fast_exp2(c1[r] - m_run);
      // tree sum
      float s8[8];
#pragma unroll
      for (int r = 0; r < 8; ++r) s8[r] = (c0[r] + c0[r + 8]) + (c1[r] + c1[r + 8]);
#pragma unroll
      for (int r = 0; r < 4; ++r) s8[r] += s8[r + 4];
      float ps = (s8[0] + s8[1]) + (s8[2] + s8[3]);
      ps += __shfl_xor(ps, 32, 64);
      l_run += ps;

      // PV in two halves: kc0,1 from c0; kc2,3 from c1
      u32 pk[8], ok[8];
#pragma unroll
      for (int half = 0; half < 2; ++half) {
#pragma unroll
        for (int q = 0; q < 4; ++q) {
#pragma unroll
          for (int hh = 0; hh < 2; ++hh) {
            float va = half ? c1[q * 4 + 2 * hh]     : c0[q * 4 + 2 * hh];
            float vb = half ? c1[q * 4 + 2 * hh + 1] : c0[q * 4 + 2 * hh + 1];
            pk[q * 2 + hh] = packbf(va, vb);
          }
        }
#pragma unroll
        for (int i = 0; i < 8; ++i) ok[i] = __shfl_xor(pk[i], 32, 64);
        __builtin_amdgcn_s_setprio(1);
#pragma unroll
        for (int kh = 0; kh < 2; ++kh) {
          int kc = half * 2 + kh;
          const int base = 4 * kh;
          u32 w0 = g ? ok[base + 2] : pk[base + 0];
          u32 w1 = g ? ok[base + 3] : pk[base + 1];
          u32 w2 = g ? pk[base + 2] : ok[base + 0];
          u32 w3 = g ? pk[base + 3] : ok[base + 1];
          u32x4 uu = {w0, w1, w2, w3};
          short8v pf = __builtin_bit_cast(short8v, uu);
          short8v v0 = ld_vt(curVT, lj,      2 * kc + g);
          short8v v1 = ld_vt(curVT, 32 + lj, 2 * kc + g);
          short8v v2 = ld_vt(curVT, 64 + lj, 2 * kc + g);
          short8v v3 = ld_vt(curVT, 96 + lj, 2 * kc + g);
          o0 = mfma_bf16(v0, pf, o0);
          o1 = mfma_bf16(v1, pf, o1);
          o2 = mfma_bf16(v2, pf, o2);
          o3 = mfma_bf16(v3, pf, o3);
        }
        __builtin_amdgcn_s_setprio(0);
      }
    }

    // next pair's loads had a full superstep of flight; drain is ~free
    asm volatile("s_waitcnt vmcnt(0)" ::: "memory");
    __builtin_amdgcn_sched_barrier(0);
    __builtin_amdgcn_s_barrier();
    __builtin_amdgcn_sched_barrier(0);
  }

  // epilogue: O /= l, store bf16 to Ows[n][j][d]
  float inv = 1.f / l_run;
  int jme = j0 + w * 32 + lj;
  u16* obase = Ows + ((size_t)n * SEQ + jme) * DMODEL;

#define STORE_OT(OV, DT)                                                  \
  {                                                                       \
    _Pragma("unroll") for (int q = 0; q < 4; ++q) {                       \
      int d0 = (DT) * 32 + 4 * g + 8 * q;                                 \
      u32x2 val;                                                          \
      val.x = bfpair(OV[4 * q + 0] * inv, OV[4 * q + 1] * inv);           \
      val.y = bfpair(OV[4 * q + 2] * inv, OV[4 * q + 3] * inv);           \
      *reinterpret_cast<u32x2*>(obase + d0) = val;                        \
    }                                                                     \
  }
  STORE_OT(o0, 0) STORE_OT(o1, 1) STORE_OT(o2, 2) STORE_OT(o3, 3)
#undef STORE_OT
#undef ISSUE_TILE
}

// ---------- projection out[b][dm][j] = sum_c Wt[dm][c] * Ows[b,c][j] ----------
__global__ __launch_bounds__(256) void proj_kernel(
    const u16* __restrict__ Ows, const u16* __restrict__ Wt, float* __restrict__ out) {
  __shared__ __align__(16) u16 BT[32 * 128];
  const int tid = threadIdx.x;
  const int w = tid >> 6, lane = tid & 63, g = lane >> 5, lj = lane & 31;
  const int b = blockIdx.x >> 6;
  const int j0 = (blockIdx.x & 63) * 32;
  f32x16 acc = fzero16();
#pragma unroll 1
  for (int h = 0; h < 16; ++h) {
    __syncthreads();
#pragma unroll
    for (int rr = 0; rr < 2; ++rr) {
      int s = tid + rr * 256;
      int r = s >> 4, cc = s & 15;
      u16x8 v = *reinterpret_cast<const u16x8*>(
          Ows + ((size_t)(b * 16 + h) * SEQ + j0 + r) * DMODEL + cc * 8);
      *reinterpret_cast<u16x8*>(BT + r * 128 + ((cc ^ (r & 7)) * 8)) = v;
    }
    __syncthreads();
#pragma unroll
    for (int kc = 0; kc < 8; ++kc) {
      short8v a = *reinterpret_cast<const short8v*>(
          Wt + (size_t)(w * 32 + lj) * SEQ + h * 128 + kc * 16 + g * 8);
      short8v bb = *reinterpret_cast<const short8v*>(
          BT + lj * 128 + (((2 * kc + g) ^ (lj & 7)) * 8));
      acc = mfma_bf16(a, bb, acc);
    }
  }
#pragma unroll
  for (int q = 0; q < 4; ++q) {
#pragma unroll
    for (int r = 0; r < 4; ++r) {
      int dm = w * 32 + 4 * g + 8 * q + r;
      out[((size_t)b * DMODEL + dm) * SEQ + j0 + lj] = acc[4 * q + r];
    }
  }
}

// ---------- host launcher ----------
extern "C" void kernel_launch(void* const* d_in, const int* in_sizes, int n_in,
                              void* d_out, int out_size, void* d_ws, size_t ws_size,
                              hipStream_t stream) {
  (void)in_sizes; (void)n_in; (void)out_size; (void)ws_size;
  const float* Q = (const float*)d_in[1];
  const float* K = (const float*)d_in[2];
  const float* V = (const float*)d_in[3];
  const float* W = (const float*)d_in[4];
  const size_t NEL = (size_t)HEADS * SEQ * DMODEL;   // 16.8M elements
  u16* Qt   = (u16*)d_ws;                // 33.5 MB
  u16* V16t = Qt + NEL;                  // 33.5 MB (tile-contiguous)
  u16* Ows  = V16t + NEL;                // 33.5 MB
  u16* Wt   = Ows + NEL;                 // 0.5 MB
  float* out = (float*)d_out;

  prep_qt<<<dim3(2048), dim3(256), 0, stream>>>(Q, Qt);
  prep_v<<<dim3(2048), dim3(256), 0, stream>>>(V, V16t);
  wtrans_kernel<<<dim3(512), dim3(256), 0, stream>>>(W, Wt);
  attn_kernel<<<dim3(512), dim3(512), 0, stream>>>(Qt, K, V16t, Ows);
  proj_kernel<<<dim3(256), dim3(256), 0, stream>>>(Ows, Wt, out);
}

// Round 6
// 238.493 us; speedup vs baseline: 1.6482x; 1.0192x over previous
//
#include <hip/hip_runtime.h>
#include <hip/hip_bf16.h>

typedef unsigned short u16;
typedef unsigned int   u32;
typedef short  short8v __attribute__((ext_vector_type(8)));
typedef u16    u16x8   __attribute__((ext_vector_type(8)));
typedef float  f32x16  __attribute__((ext_vector_type(16)));
typedef float  f32x4v  __attribute__((ext_vector_type(4)));
typedef u32    u32x2   __attribute__((ext_vector_type(2)));
typedef u32    u32x4   __attribute__((ext_vector_type(4)));

#define HEADS 64
#define DMODEL 128
#define SEQ 2048

// log2(e)/sqrt(128), folded into Qt during prep
#define SCQ 0.1275293f

// ---------- helpers ----------

__device__ __forceinline__ f32x16 mfma_bf16(short8v a, short8v b, f32x16 c) {
  return __builtin_amdgcn_mfma_f32_32x32x16_bf16(a, b, c, 0, 0, 0);
}

__device__ __forceinline__ f32x16 fzero16() {
  f32x16 z;
#pragma unroll
  for (int i = 0; i < 16; ++i) z[i] = 0.f;
  return z;
}

__device__ __forceinline__ float fast_exp2(float x) {
  float r;
  asm("v_exp_f32 %0, %1" : "=v"(r) : "v"(x));   // v_exp_f32 IS exp2
  return r;
}

// round-to-nearest-even f32 -> bf16 bits
__device__ __forceinline__ u32 bfround(float x) {
  u32 u = __builtin_bit_cast(u32, x);
  u += 0x7fffu + ((u >> 16) & 1u);
  return u >> 16;
}
__device__ __forceinline__ u32 bfpair(float lo, float hi) {
  u32 a = __builtin_bit_cast(u32, lo); a += 0x7fffu + ((a >> 16) & 1u);
  u32 b = __builtin_bit_cast(u32, hi); b += 0x7fffu + ((b >> 16) & 1u);
  return (a >> 16) | (b & 0xffff0000u);
}
// hot-loop pack -> v_cvt_pk_bf16_f32 via compiler (m240)
__device__ __forceinline__ u32 packbf(float lo, float hi) {
  u32 l16 = (u32)__builtin_bit_cast(u16, __float2bfloat16(lo));
  u32 h16 = (u32)__builtin_bit_cast(u16, __float2bfloat16(hi));
  return l16 | (h16 << 16);
}

// async global->LDS, 16B/lane, dest = wave-uniform base + lane*16
typedef const __attribute__((address_space(1))) void* gp1_t;
typedef __attribute__((address_space(3))) void* lp3_t;
__device__ __forceinline__ void gload16(const u16* g, u16* l) {
  __builtin_amdgcn_global_load_lds((gp1_t)g, (lp3_t)l, 16, 0, 0);
}

// K-prologue transposing stage (512 threads): src [128 d][2048 pos] f32 ->
// LDS tile [64 pos][128 d] bf16, chunk' = chunk ^ (row & 15)
__device__ __forceinline__ void stage_T(const float* __restrict__ src, int pos0,
                                        u16* lds, int tid) {
  int ic = tid & 7;
  int d0 = (tid >> 3) * 2;
  const float* p = src + d0 * SEQ + pos0 + ic * 8;
  f32x4v xa = *reinterpret_cast<const f32x4v*>(p);
  f32x4v xb = *reinterpret_cast<const f32x4v*>(p + 4);
  f32x4v ya = *reinterpret_cast<const f32x4v*>(p + SEQ);
  f32x4v yb = *reinterpret_cast<const f32x4v*>(p + SEQ + 4);
  u32* lds32 = reinterpret_cast<u32*>(lds);
  int cc = d0 >> 3;
#pragma unroll
  for (int k = 0; k < 8; ++k) {
    int r = ic * 8 + k;
    int c2 = cc ^ (r & 15);
    float xv = (k < 4) ? xa[k & 3] : xb[k & 3];
    float yv = (k < 4) ? ya[k & 3] : yb[k & 3];
    lds32[(r * 128 + c2 * 8 + (d0 & 7)) >> 1] = bfpair(xv, yv);
  }
}

// fragment reads (ds_read_b128), undoing the XOR swizzles
__device__ __forceinline__ short8v ld_at(const u16* lds, int row, int chunk) {
  return *reinterpret_cast<const short8v*>(lds + row * 128 + ((chunk ^ (row & 15)) * 8));
}
__device__ __forceinline__ short8v ld_vt(const u16* lds, int d, int chunk) {
  return *reinterpret_cast<const short8v*>(lds + d * 64 + ((chunk ^ (d & 7)) * 8));
}

// ---------- prep kernels ----------

// Q f32 [n][128 d][2048 s] -> Qt bf16 [n][2048 s][128 d], scaled by SCQ
__global__ __launch_bounds__(256) void prep_qt(const float* __restrict__ Q,
                                               u16* __restrict__ Qt) {
  int blk = blockIdx.x;            // 64 heads * 32 pos-tiles
  int n = blk >> 5, pt = blk & 31;
  const float* src = Q + (size_t)n * DMODEL * SEQ;
  u16* dst = Qt + (size_t)n * SEQ * DMODEL + (size_t)pt * 64 * DMODEL;
  int t = threadIdx.x;
  int pq = t & 15, dq = t >> 4;
#pragma unroll
  for (int p = 0; p < 2; ++p) {
    int d0 = (dq + 16 * p) * 4;
    const float* s0 = src + (size_t)d0 * SEQ + pt * 64 + pq * 4;
    f32x4v r0 = *reinterpret_cast<const f32x4v*>(s0);
    f32x4v r1 = *reinterpret_cast<const f32x4v*>(s0 + SEQ);
    f32x4v r2 = *reinterpret_cast<const f32x4v*>(s0 + 2 * SEQ);
    f32x4v r3 = *reinterpret_cast<const f32x4v*>(s0 + 3 * SEQ);
#pragma unroll
    for (int j = 0; j < 4; ++j) {
      u32x2 v = { bfpair(r0[j] * SCQ, r1[j] * SCQ), bfpair(r2[j] * SCQ, r3[j] * SCQ) };
      *reinterpret_cast<u32x2*>(dst + (pq * 4 + j) * DMODEL + d0) = v;
    }
  }
}

// V f32 [n][128 d][2048 s] -> tile-contiguous bf16 [n][it(32)][128 d][64 s]
__global__ __launch_bounds__(256) void prep_v(const float* __restrict__ V,
                                              u16* __restrict__ V16t) {
  int blk = blockIdx.x;            // n*32 + it
  int n = blk >> 5, it = blk & 31;
  int t = threadIdx.x;
  int s8 = (t & 7) * 8;
  const float* src = V + (size_t)n * DMODEL * SEQ + it * 64 + s8;
  u16* dst = V16t + (size_t)blk * DMODEL * 64 + s8;
#pragma unroll
  for (int rr = 0; rr < 4; ++rr) {
    int d = (t >> 3) + 32 * rr;
    const float* p = src + (size_t)d * SEQ;
    f32x4v a = *reinterpret_cast<const f32x4v*>(p);
    f32x4v b = *reinterpret_cast<const f32x4v*>(p + 4);
    u32x4 v = { bfpair(a[0], a[1]), bfpair(a[2], a[3]),
                bfpair(b[0], b[1]), bfpair(b[2], b[3]) };
    *reinterpret_cast<u32x4*>(dst + d * 64) = v;
  }
}

// W transpose (f32 [2048][128] -> bf16 [128][2048])
__global__ void wtrans_kernel(const float* __restrict__ Wsrc, u16* __restrict__ Wt) {
  int e = blockIdx.x * 256 + threadIdx.x;
#pragma unroll
  for (int rr = 0; rr < 2; ++rr) {
    int o = e + rr * 131072;
    int dm = o >> 11, c = o & 2047;
    Wt[o] = (u16)bfround(Wsrc[c * 128 + dm]);
  }
}

// ---------- flash attention, wave-specialized producer/consumer ----------
// 512 blocks = head(64) x jblock(8 x 256 j), head%8 -> XCD.
// 1024 threads = 16 waves: w 0-7 producers (QK^T+softmax, j-slice w),
//                          w 8-15 consumers (PV+O, j-slice w-8).
// Per step t: producer computes P(t) -> LDS; consumer applies P(t-1).
__global__ __launch_bounds__(1024, 4) void attn_kernel(
    const u16* __restrict__ Qt, const float* __restrict__ K,
    const u16* __restrict__ V16t, u16* __restrict__ Ows) {
  __shared__ __align__(16) u16 AT2[2][64 * DMODEL];    // 2x16KB Q tiles
  __shared__ __align__(16) u16 VT2[2][DMODEL * 64];    // 2x16KB V tiles
  __shared__ __align__(16) u16 PB[2][256 * 64];        // 2x32KB P tiles
  __shared__ float AL[2][256];                         // alpha per j
  __shared__ float LL[256];                            // final l per j
  const int tid = threadIdx.x;
  const int w = tid >> 6;
  const int lane = tid & 63;
  const int g = lane >> 5;
  const int lj = lane & 31;
  const int p_ = blockIdx.x;
  const int n = ((p_ >> 6) << 3) | (p_ & 7);
  const int j0 = ((p_ >> 3) & 7) * 256;
  const u16* Qtn = Qt + (size_t)n * SEQ * DMODEL;
  const float* Kb = K + (size_t)n * DMODEL * SEQ;
  const u16* Vtn = V16t + (size_t)n * 32 * DMODEL * 64;

  // staging lane offsets (2 gload16 per wave per tile; pre-swizzled source)
  int qoff[2], voff[2];
#pragma unroll
  for (int i = 0; i < 2; ++i) {
    int idx = (w & 7) * 2 + i;
    int pos = idx * 4 + (lane >> 4);
    qoff[i] = pos * DMODEL + (((lane & 15) ^ (pos & 15)) * 8);
    int d = idx * 8 + (lane >> 3);
    voff[i] = d * 64 + (((lane & 7) ^ (d & 7)) * 8);
  }

  // ---- shared prologue: K rows for producers; prime A(0) ----
  if (w < 8) {
    const u16* qb = Qtn;  // tile 0
#pragma unroll
    for (int i = 0; i < 2; ++i)
      gload16(qb + qoff[i], AT2[0] + ((w & 7) * 2 + i) * 512);
  }
  short8v bq[8];
  u16* KS = PB[0];   // 32KB scratch, free before main loop
#pragma unroll 1
  for (int p = 0; p < 4; ++p) {
    if (tid < 512) stage_T(Kb, j0 + p * 64, KS, tid);
    __syncthreads();
    if (w < 8 && (w >> 1) == p) {
      int row = (w & 1) * 32 + lj;
#pragma unroll
      for (int c = 0; c < 8; ++c) bq[c] = ld_at(KS, row, 2 * c + g);
    }
    __syncthreads();
  }

  if (w < 8) {
    // =================== PRODUCER ===================
    float m_run = -1e30f, l_run = 0.f;
    const int prow = w * 32 + lj;
    u16* const prowbase0 = PB[0] + prow * 64;
    u16* const prowbase1 = PB[1] + prow * 64;
    const int swz = prow & 7;

#pragma unroll 1
    for (int t = 0; t <= 32; ++t) {
      if (t < 32) {
        // issue A(t+1)
        const u16* qb = Qtn + (size_t)((t + 1) & 31) * (64 * DMODEL);
        u16* ab = AT2[(t + 1) & 1];
#pragma unroll
        for (int i = 0; i < 2; ++i)
          gload16(qb + qoff[i], ab + ((w & 7) * 2 + i) * 512);

        const u16* curAT = AT2[t & 1];
        f32x16 c0 = fzero16(), c1 = fzero16();
        __builtin_amdgcn_s_setprio(1);
#pragma unroll
        for (int dc = 0; dc < 8; ++dc) {
          short8v a0 = ld_at(curAT, lj, 2 * dc + g);
          short8v a1 = ld_at(curAT, 32 + lj, 2 * dc + g);
          c0 = mfma_bf16(a0, bq[dc], c0);
          c1 = mfma_bf16(a1, bq[dc], c1);
        }
        __builtin_amdgcn_s_setprio(0);

        // tree max over 32 lane-local values, then pair-combine
        float m8[8];
#pragma unroll
        for (int r = 0; r < 8; ++r)
          m8[r] = fmaxf(fmaxf(c0[r], c0[r + 8]), fmaxf(c1[r], c1[r + 8]));
#pragma unroll
        for (int r = 0; r < 4; ++r) m8[r] = fmaxf(m8[r], m8[r + 4]);
        float mx = fmaxf(fmaxf(m8[0], m8[1]), fmaxf(m8[2], m8[3]));
        mx = fmaxf(mx, __shfl_xor(mx, 32, 64));

        float al = 1.0f;
        if (!__all(mx <= m_run + 8.f)) {   // defer-max (T13)
          float mn = fmaxf(m_run, mx);
          al = fast_exp2(m_run - mn);
          m_run = mn;
          l_run *= al;
        }
        if (!g) AL[t & 1][prow] = al;

#pragma unroll
        for (int r = 0; r < 16; ++r) c0[r] = fast_exp2(c0[r] - m_run);
#pragma unroll
        for (int r = 0; r < 16; ++r) c1[r] = fast_exp2(c1[r] - m_run);
        float s8[8];
#pragma unroll
        for (int r = 0; r < 8; ++r) s8[r] = (c0[r] + c0[r + 8]) + (c1[r] + c1[r + 8]);
#pragma unroll
        for (int r = 0; r < 4; ++r) s8[r] += s8[r + 4];
        float ps = (s8[0] + s8[1]) + (s8[2] + s8[3]);
        ps += __shfl_xor(ps, 32, 64);
        l_run += ps;

        // pack P -> LDS. c half H covers i = 32H + 8q + 4g + [0,4): granule
        // G = q + 4H, swizzled G^swz, intra-granule u16 offset 4g.
        u16* pdst = (t & 1) ? prowbase1 : prowbase0;
#pragma unroll
        for (int half = 0; half < 2; ++half) {
#pragma unroll
          for (int q = 0; q < 4; ++q) {
            u32x2 val;
            val.x = half ? packbf(c1[4 * q + 0], c1[4 * q + 1])
                         : packbf(c0[4 * q + 0], c0[4 * q + 1]);
            val.y = half ? packbf(c1[4 * q + 2], c1[4 * q + 3])
                         : packbf(c0[4 * q + 2], c0[4 * q + 3]);
            int G = q + 4 * half;
            *reinterpret_cast<u32x2*>(pdst + ((G ^ swz) << 3) + 4 * g) = val;
          }
        }
      }
      __syncthreads();
    }
    if (!g) LL[prow] = l_run;
    __syncthreads();
    // producer done (no store)
  } else {
    // =================== CONSUMER ===================
    f32x16 o0 = fzero16(), o1 = fzero16(), o2 = fzero16(), o3 = fzero16();
    const int prow = (w - 8) * 32 + lj;
    const int swz = prow & 7;

#pragma unroll 1
    for (int t = 0; t <= 32; ++t) {
      if (t < 32) {
        // issue V(t)
        const u16* vb = Vtn + (size_t)t * (DMODEL * 64);
        u16* vbuf = VT2[t & 1];
#pragma unroll
        for (int i = 0; i < 2; ++i)
          gload16(vb + voff[i], vbuf + ((w & 7) * 2 + i) * 512);
      }
      if (t >= 1) {
        const int tp = t - 1;
        const u16* curVT = VT2[tp & 1];
        const u16* prowp = PB[tp & 1] + prow * 64;
        float al = AL[tp & 1][prow];
        if (!__all(al == 1.0f)) {
#pragma unroll
          for (int r = 0; r < 16; ++r) { o0[r] *= al; o1[r] *= al; o2[r] *= al; o3[r] *= al; }
        }
        __builtin_amdgcn_s_setprio(1);
#pragma unroll
        for (int kc = 0; kc < 4; ++kc) {
          short8v pf = *reinterpret_cast<const short8v*>(
              prowp + (((2 * kc + g) ^ swz) << 3));
          short8v v0 = ld_vt(curVT, lj,      2 * kc + g);
          short8v v1 = ld_vt(curVT, 32 + lj, 2 * kc + g);
          short8v v2 = ld_vt(curVT, 64 + lj, 2 * kc + g);
          short8v v3 = ld_vt(curVT, 96 + lj, 2 * kc + g);
          o0 = mfma_bf16(v0, pf, o0);
          o1 = mfma_bf16(v1, pf, o1);
          o2 = mfma_bf16(v2, pf, o2);
          o3 = mfma_bf16(v3, pf, o3);
        }
        __builtin_amdgcn_s_setprio(0);
      }
      __syncthreads();
    }
    __syncthreads();   // matches producer's LL-publish barrier
    float inv = 1.f / LL[prow];
    int jme = j0 + prow;
    u16* obase = Ows + ((size_t)n * SEQ + jme) * DMODEL;
#define STORE_OT(OV, DT)                                                  \
    {                                                                     \
      _Pragma("unroll") for (int q = 0; q < 4; ++q) {                     \
        int d0 = (DT) * 32 + 4 * g + 8 * q;                               \
        u32x2 val;                                                        \
        val.x = bfpair(OV[4 * q + 0] * inv, OV[4 * q + 1] * inv);         \
        val.y = bfpair(OV[4 * q + 2] * inv, OV[4 * q + 3] * inv);         \
        *reinterpret_cast<u32x2*>(obase + d0) = val;                      \
      }                                                                   \
    }
    STORE_OT(o0, 0) STORE_OT(o1, 1) STORE_OT(o2, 2) STORE_OT(o3, 3)
#undef STORE_OT
  }
}

// ---------- projection out[b][dm][j] = sum_c Wt[dm][c] * Ows[b,c][j] ----------
__global__ __launch_bounds__(256) void proj_kernel(
    const u16* __restrict__ Ows, const u16* __restrict__ Wt, float* __restrict__ out) {
  __shared__ __align__(16) u16 BT[32 * 128];
  const int tid = threadIdx.x;
  const int w = tid >> 6, lane = tid & 63, g = lane >> 5, lj = lane & 31;
  const int b = blockIdx.x >> 6;
  const int j0 = (blockIdx.x & 63) * 32;
  f32x16 acc = fzero16();
#pragma unroll 1
  for (int h = 0; h < 16; ++h) {
    __syncthreads();
#pragma unroll
    for (int rr = 0; rr < 2; ++rr) {
      int s = tid + rr * 256;
      int r = s >> 4, cc = s & 15;
      u16x8 v = *reinterpret_cast<const u16x8*>(
          Ows + ((size_t)(b * 16 + h) * SEQ + j0 + r) * DMODEL + cc * 8);
      *reinterpret_cast<u16x8*>(BT + r * 128 + ((cc ^ (r & 7)) * 8)) = v;
    }
    __syncthreads();
#pragma unroll
    for (int kc = 0; kc < 8; ++kc) {
      short8v a = *reinterpret_cast<const short8v*>(
          Wt + (size_t)(w * 32 + lj) * SEQ + h * 128 + kc * 16 + g * 8);
      short8v bb = *reinterpret_cast<const short8v*>(
          BT + lj * 128 + (((2 * kc + g) ^ (lj & 7)) * 8));
      acc = mfma_bf16(a, bb, acc);
    }
  }
#pragma unroll
  for (int q = 0; q < 4; ++q) {
#pragma unroll
    for (int r = 0; r < 4; ++r) {
      int dm = w * 32 + 4 * g + 8 * q + r;
      out[((size_t)b * DMODEL + dm) * SEQ + j0 + lj] = acc[4 * q + r];
    }
  }
}

// ---------- host launcher ----------
extern "C" void kernel_launch(void* const* d_in, const int* in_sizes, int n_in,
                              void* d_out, int out_size, void* d_ws, size_t ws_size,
                              hipStream_t stream) {
  (void)in_sizes; (void)n_in; (void)out_size; (void)ws_size;
  const float* Q = (const float*)d_in[1];
  const float* K = (const float*)d_in[2];
  const float* V = (const float*)d_in[3];
  const float* W = (const float*)d_in[4];
  const size_t NEL = (size_t)HEADS * SEQ * DMODEL;   // 16.8M elements
  u16* Qt   = (u16*)d_ws;                // 33.5 MB
  u16* V16t = Qt + NEL;                  // 33.5 MB (tile-contiguous)
  u16* Ows  = V16t + NEL;                // 33.5 MB
  u16* Wt   = Ows + NEL;                 // 0.5 MB
  float* out = (float*)d_out;

  prep_qt<<<dim3(2048), dim3(256), 0, stream>>>(Q, Qt);
  prep_v<<<dim3(2048), dim3(256), 0, stream>>>(V, V16t);
  wtrans_kernel<<<dim3(512), dim3(256), 0, stream>>>(W, Wt);
  attn_kernel<<<dim3(512), dim3(1024), 0, stream>>>(Qt, K, V16t, Ows);
  proj_kernel<<<dim3(256), dim3(256), 0, stream>>>(Ows, Wt, out);
}